// Round 1
// baseline (506.162 us; speedup 1.0000x reference)
//
#include <hip/hip_runtime.h>

#define HID 768
#define NH 12
#define LSEQ 512
#define BS 16
#define WLEN 2048
#define AD 64

typedef unsigned short u16;
typedef short short8 __attribute__((ext_vector_type(8)));
typedef float f32x4 __attribute__((ext_vector_type(4)));

#define MFMA16(a, b, c) __builtin_amdgcn_mfma_f32_16x16x32_bf16((a), (b), (c), 0, 0, 0)

__device__ __forceinline__ u16 f2bf(float f) {
  union { float f; unsigned u; } v; v.f = f;
  unsigned u = v.u;
  return (u16)((u + 0x7fffu + ((u >> 16) & 1u)) >> 16);  // RNE
}

// ---------------------------------------------------------------- transpose+convert
// dst[n][k] = bf16(W[k][n]); one 64x64 tile per block.
__global__ __launch_bounds__(256) void transpose_kernel(const float* __restrict__ W,
                                                        u16* __restrict__ dst) {
  __shared__ float tile[64][65];
  const int k0 = blockIdx.x * 64, n0 = blockIdx.y * 64;
  for (int i = threadIdx.x; i < 64 * 64; i += 256) {
    const int r = i >> 6, c = i & 63;
    tile[r][c] = W[(size_t)(k0 + r) * HID + n0 + c];
  }
  __syncthreads();
  for (int i = threadIdx.x; i < 64 * 64; i += 256) {
    const int r = i >> 6, c = i & 63;
    dst[(size_t)(n0 + r) * HID + k0 + c] = f2bf(tile[c][r]);
  }
}

// ---------------------------------------------------------------- walk-node weights
// counts_front: bincount, compact nonzero counts to the front (in node-id order).
// weight[b][slot] = count/WLEN * n_nodes[b]; zero elsewhere.
__global__ __launch_bounds__(512) void counts_kernel(const int* __restrict__ wn,
                                                     const int* __restrict__ nn,
                                                     float* __restrict__ wgt) {
  __shared__ int cnt[LSEQ];
  __shared__ int sc[2][LSEQ];
  const int b = blockIdx.x, t = threadIdx.x;
  cnt[t] = 0;
  __syncthreads();
  for (int i = t; i < WLEN; i += 512) atomicAdd(&cnt[wn[b * WLEN + i]], 1);
  __syncthreads();
  const int c = cnt[t];
  const int nz = c > 0 ? 1 : 0;
  sc[0][t] = nz;
  __syncthreads();
  int src = 0;
  for (int step = 1; step < LSEQ; step <<= 1) {
    int v = sc[src][t];
    if (t >= step) v += sc[src][t - step];
    sc[src ^ 1][t] = v;
    __syncthreads();
    src ^= 1;
  }
  wgt[b * LSEQ + t] = 0.0f;
  __syncthreads();
  if (nz) {
    const int slot = sc[src][t] - 1;
    wgt[b * LSEQ + slot] = (float)c * (float)nn[b] * (1.0f / WLEN);
  }
}

// ---------------------------------------------------------------- LayerNorm -> bf16
// one wave per row of 768; 12 f32 per lane (3x float4), shfl-xor reduce.
__global__ __launch_bounds__(256) void ln_kernel(const float* __restrict__ x,
                                                 const float* __restrict__ g,
                                                 const float* __restrict__ bb,
                                                 u16* __restrict__ xn) {
  const int w = threadIdx.x >> 6, lane = threadIdx.x & 63;
  const int row = blockIdx.x * 4 + w;
  const float* xr = x + (size_t)row * HID + lane * 12;
  float4 v0 = *(const float4*)(xr);
  float4 v1 = *(const float4*)(xr + 4);
  float4 v2 = *(const float4*)(xr + 8);
  float vv[12] = {v0.x, v0.y, v0.z, v0.w, v1.x, v1.y, v1.z, v1.w, v2.x, v2.y, v2.z, v2.w};
  float s = 0.f, q = 0.f;
#pragma unroll
  for (int j = 0; j < 12; ++j) { s += vv[j]; q += vv[j] * vv[j]; }
#pragma unroll
  for (int d = 1; d < 64; d <<= 1) { s += __shfl_xor(s, d); q += __shfl_xor(q, d); }
  const float mean = s * (1.0f / HID);
  const float var = q * (1.0f / HID) - mean * mean;
  const float rs = rsqrtf(var + 1e-5f);
  const float* gp = g + lane * 12;
  const float* bp = bb + lane * 12;
  unsigned pk[6];
#pragma unroll
  for (int j = 0; j < 6; ++j) {
    const u16 lo = f2bf((vv[2 * j] - mean) * rs * gp[2 * j] + bp[2 * j]);
    const u16 hi = f2bf((vv[2 * j + 1] - mean) * rs * gp[2 * j + 1] + bp[2 * j + 1]);
    pk[j] = (unsigned)lo | ((unsigned)hi << 16);
  }
  unsigned* dst = (unsigned*)(xn + (size_t)row * HID + lane * 12);
#pragma unroll
  for (int j = 0; j < 6; ++j) dst[j] = pk[j];
}

// ---------------------------------------------------------------- MFMA GEMM
// A [Mrows][768] bf16 row-major, Bt [Ncols][768] bf16 (B transposed).
// 128x128 tile, BK=32, 4 waves (2x2), 4x4 16x16x32 fragments per wave.
// MODE 0: QKV epilogue (scale q, reweight v, scatter to [b][h][l][d] / vT).
// MODE 1: out = acc + bo -> f32.
template <int MODE>
__global__ __launch_bounds__(256) void gemm_kernel(
    const u16* __restrict__ A, const u16* __restrict__ Bt,
    const float* __restrict__ bias0, const float* __restrict__ bias1,
    const float* __restrict__ bias2, const float* __restrict__ wgt,
    u16* __restrict__ qb, u16* __restrict__ kb, u16* __restrict__ vt,
    float* __restrict__ outf) {
  __shared__ u16 at[128][40];
  __shared__ u16 bt[128][40];
  const int tid = threadIdx.x;
  const int lane = tid & 63, w = tid >> 6;
  const int wr = w >> 1, wc = w & 1;
  const int fr = lane & 15, fc = lane >> 4;
  const int row0 = blockIdx.x * 128, col0 = blockIdx.y * 128;

  const f32x4 zero4 = {0.f, 0.f, 0.f, 0.f};
  f32x4 acc[4][4];
#pragma unroll
  for (int m = 0; m < 4; ++m)
#pragma unroll
    for (int n = 0; n < 4; ++n) acc[m][n] = zero4;

  const int srow = tid >> 1, soff = (tid & 1) * 16;
  const u16* aptr = A + (size_t)(row0 + srow) * HID + soff;
  const u16* bptr = Bt + (size_t)(col0 + srow) * HID + soff;

  for (int kt = 0; kt < HID / 32; ++kt) {
    const short8 a0 = *(const short8*)(aptr);
    const short8 a1 = *(const short8*)(aptr + 8);
    const short8 b0 = *(const short8*)(bptr);
    const short8 b1 = *(const short8*)(bptr + 8);
    aptr += 32; bptr += 32;
    __syncthreads();
    *(short8*)&at[srow][soff] = a0;
    *(short8*)&at[srow][soff + 8] = a1;
    *(short8*)&bt[srow][soff] = b0;
    *(short8*)&bt[srow][soff + 8] = b1;
    __syncthreads();
    short8 af[4], bfr[4];
#pragma unroll
    for (int m = 0; m < 4; ++m) af[m] = *(const short8*)&at[wr * 64 + m * 16 + fr][fc * 8];
#pragma unroll
    for (int n = 0; n < 4; ++n) bfr[n] = *(const short8*)&bt[wc * 64 + n * 16 + fr][fc * 8];
#pragma unroll
    for (int m = 0; m < 4; ++m)
#pragma unroll
      for (int n = 0; n < 4; ++n)
        acc[m][n] = MFMA16(af[m], bfr[n], acc[m][n]);
  }

  if (MODE == 0) {
    const int reg = col0 / HID;  // uniform per block (768 % 128 == 0)
    const float* bias = (reg == 0) ? bias0 : (reg == 1) ? bias1 : bias2;
#pragma unroll
    for (int m = 0; m < 4; ++m) {
      const int row = row0 + wr * 64 + m * 16 + fc * 4;
      const int b = row >> 9;
      const int tok0 = row & 511;
#pragma unroll
      for (int n = 0; n < 4; ++n) {
        const int cc = (col0 - reg * HID) + wc * 64 + n * 16 + fr;
        const int h = cc >> 6, d = cc & 63;
        const float bval = bias[cc];
#pragma unroll
        for (int r = 0; r < 4; ++r) {
          const float v = acc[m][n][r] + bval;
          const int tok = tok0 + r;
          if (reg == 0)
            qb[(((size_t)b * NH + h) * LSEQ + tok) * AD + d] = f2bf(v * 0.125f);
          else if (reg == 1)
            kb[(((size_t)b * NH + h) * LSEQ + tok) * AD + d] = f2bf(v);
          else
            vt[(((size_t)b * NH + h) * AD + d) * LSEQ + tok] = f2bf(v * wgt[b * LSEQ + tok]);
        }
      }
    }
  } else {
#pragma unroll
    for (int m = 0; m < 4; ++m) {
      const int row = row0 + wr * 64 + m * 16 + fc * 4;
#pragma unroll
      for (int n = 0; n < 4; ++n) {
        const int col = col0 + wc * 64 + n * 16 + fr;
        const float bval = bias0[col];
#pragma unroll
        for (int r = 0; r < 4; ++r)
          outf[(size_t)(row + r) * HID + col] = acc[m][n][r] + bval;
      }
    }
  }
}

// ---------------------------------------------------------------- flash attention
// grid: (b*NH+h)*8 + qtile. 4 waves; wave w owns 16 q-rows. KV tiles of 64.
// bias preloaded into MFMA C operand; online softmax; P transposed via per-wave LDS.
__global__ __launch_bounds__(256) void attn_kernel(const u16* __restrict__ qb,
                                                   const u16* __restrict__ kb,
                                                   const u16* __restrict__ vt,
                                                   const float* __restrict__ bias,
                                                   u16* __restrict__ aout) {
  __shared__ u16 p_lds[4][16][72];
  const int tid = threadIdx.x;
  const int w = tid >> 6, lane = tid & 63;
  const int fr = lane & 15, fc = lane >> 4;
  const int blk = blockIdx.x;
  const int qt = blk & 7, bh = blk >> 3;
  const int h = bh % NH, b = bh / NH;
  const int q0 = qt * 64 + w * 16;

  const u16* qbase = qb + (size_t)bh * LSEQ * AD;
  const u16* kbase = kb + (size_t)bh * LSEQ * AD;
  const u16* vbase = vt + (size_t)bh * AD * LSEQ;
  const float* bbase = bias + (size_t)bh * LSEQ * LSEQ;

  const short8 aq0 = *(const short8*)(qbase + (size_t)(q0 + fr) * AD + fc * 8);
  const short8 aq1 = *(const short8*)(qbase + (size_t)(q0 + fr) * AD + 32 + fc * 8);

  const f32x4 zero4 = {0.f, 0.f, 0.f, 0.f};
  f32x4 o[4];
  float m_r[4], l_r[4];
#pragma unroll
  for (int f = 0; f < 4; ++f) o[f] = zero4;
#pragma unroll
  for (int r = 0; r < 4; ++r) { m_r[r] = -3.0e38f; l_r[r] = 0.f; }

  for (int kt = 0; kt < 8; ++kt) {
    const int kv0 = kt * 64;
    f32x4 s[4];
#pragma unroll
    for (int f = 0; f < 4; ++f) {
      const float* bp = bbase + (size_t)(q0 + fc * 4) * LSEQ + kv0 + f * 16 + fr;
#pragma unroll
      for (int r = 0; r < 4; ++r) s[f][r] = bp[(size_t)r * LSEQ];
    }
#pragma unroll
    for (int f = 0; f < 4; ++f) {
      const u16* kp = kbase + (size_t)(kv0 + f * 16 + fr) * AD + fc * 8;
      const short8 k0v = *(const short8*)kp;
      const short8 k1v = *(const short8*)(kp + 32);
      s[f] = MFMA16(aq0, k0v, s[f]);
      s[f] = MFMA16(aq1, k1v, s[f]);
    }
    float alpha[4];
#pragma unroll
    for (int r = 0; r < 4; ++r) {
      float mx = fmaxf(fmaxf(s[0][r], s[1][r]), fmaxf(s[2][r], s[3][r]));
#pragma unroll
      for (int d = 1; d < 16; d <<= 1) mx = fmaxf(mx, __shfl_xor(mx, d));
      const float mn = fmaxf(m_r[r], mx);
      alpha[r] = __expf(m_r[r] - mn);
      m_r[r] = mn;
      float ps = 0.f;
#pragma unroll
      for (int f = 0; f < 4; ++f) {
        const float p = __expf(s[f][r] - mn);
        s[f][r] = p;
        ps += p;
      }
#pragma unroll
      for (int d = 1; d < 16; d <<= 1) ps += __shfl_xor(ps, d);
      l_r[r] = l_r[r] * alpha[r] + ps;
    }
#pragma unroll
    for (int f = 0; f < 4; ++f)
#pragma unroll
      for (int r = 0; r < 4; ++r) o[f][r] *= alpha[r];
    // P -> bf16 -> per-wave LDS (D-layout to A-layout transpose)
#pragma unroll
    for (int f = 0; f < 4; ++f)
#pragma unroll
      for (int r = 0; r < 4; ++r) p_lds[w][fc * 4 + r][f * 16 + fr] = f2bf(s[f][r]);
    const short8 pa0 = *(const short8*)&p_lds[w][fr][fc * 8];
    const short8 pa1 = *(const short8*)&p_lds[w][fr][32 + fc * 8];
#pragma unroll
    for (int f = 0; f < 4; ++f) {
      const u16* vp = vbase + (size_t)(f * 16 + fr) * LSEQ + kv0 + fc * 8;
      const short8 v0 = *(const short8*)vp;
      const short8 v1 = *(const short8*)(vp + 32);
      o[f] = MFMA16(pa0, v0, o[f]);
      o[f] = MFMA16(pa1, v1, o[f]);
    }
  }
#pragma unroll
  for (int f = 0; f < 4; ++f)
#pragma unroll
    for (int r = 0; r < 4; ++r) {
      const float val = o[f][r] / l_r[r];
      const int row = b * LSEQ + q0 + fc * 4 + r;
      const int col = h * AD + f * 16 + fr;
      aout[(size_t)row * HID + col] = f2bf(val);
    }
}

// ----------------------------------------------------------------
extern "C" void kernel_launch(void* const* d_in, const int* in_sizes, int n_in,
                              void* d_out, int out_size, void* d_ws, size_t ws_size,
                              hipStream_t stream) {
  const float* x = (const float*)d_in[0];
  const float* bias = (const float*)d_in[1];
  const int* wn = (const int*)d_in[2];
  const int* nn = (const int*)d_in[3];
  const float* lng = (const float*)d_in[4];
  const float* lnb = (const float*)d_in[5];
  const float* Wq = (const float*)d_in[6];
  const float* bq = (const float*)d_in[7];
  const float* Wk = (const float*)d_in[8];
  const float* bk = (const float*)d_in[9];
  const float* Wv = (const float*)d_in[10];
  const float* bv = (const float*)d_in[11];
  const float* Wo = (const float*)d_in[12];
  const float* bo = (const float*)d_in[13];
  float* out = (float*)d_out;

  char* ws = (char*)d_ws;
  float* wgt = (float*)ws;                        // 16*512*4 = 32 KB
  u16* xn = (u16*)(ws + 32768);                   // 8192*768
  u16* wt = xn + (size_t)8192 * 768;              // 2304*768
  u16* wot = wt + (size_t)2304 * 768;             // 768*768
  u16* qb = wot + (size_t)768 * 768;              // 16*12*512*64
  u16* kb = qb + (size_t)BS * NH * LSEQ * AD;
  u16* vt = kb + (size_t)BS * NH * LSEQ * AD;
  u16* aout = xn;  // alias: xn is dead after gemm<0>

  hipLaunchKernelGGL(transpose_kernel, dim3(12, 12), dim3(256), 0, stream, Wq, wt);
  hipLaunchKernelGGL(transpose_kernel, dim3(12, 12), dim3(256), 0, stream, Wk,
                     wt + (size_t)768 * 768);
  hipLaunchKernelGGL(transpose_kernel, dim3(12, 12), dim3(256), 0, stream, Wv,
                     wt + (size_t)2 * 768 * 768);
  hipLaunchKernelGGL(transpose_kernel, dim3(12, 12), dim3(256), 0, stream, Wo, wot);
  hipLaunchKernelGGL(counts_kernel, dim3(BS), dim3(512), 0, stream, wn, nn, wgt);
  hipLaunchKernelGGL(ln_kernel, dim3(2048), dim3(256), 0, stream, x, lng, lnb, xn);
  hipLaunchKernelGGL((gemm_kernel<0>), dim3(64, 18), dim3(256), 0, stream, xn, wt, bq, bk,
                     bv, wgt, qb, kb, vt, (float*)nullptr);
  hipLaunchKernelGGL(attn_kernel, dim3(1536), dim3(256), 0, stream, qb, kb, vt, bias, aout);
  hipLaunchKernelGGL((gemm_kernel<1>), dim3(64, 6), dim3(256), 0, stream, aout, wot, bo,
                     (const float*)nullptr, (const float*)nullptr, (const float*)nullptr,
                     (u16*)nullptr, (u16*)nullptr, (u16*)nullptr, out);
}

// Round 6
// 473.130 us; speedup vs baseline: 1.0698x; 1.0698x over previous
//
#include <hip/hip_runtime.h>

#define HID 768
#define NH 12
#define LSEQ 512
#define BS 16
#define WLEN 2048
#define AD 64

typedef unsigned short u16;
typedef unsigned int u32;
typedef short short8 __attribute__((ext_vector_type(8)));
typedef float f32x4 __attribute__((ext_vector_type(4)));

#define MFMA16(a, b, c) __builtin_amdgcn_mfma_f32_16x16x32_bf16((a), (b), (c), 0, 0, 0)

__device__ __forceinline__ u16 f2bf(float f) {
  union { float f; u32 u; } v; v.f = f;
  u32 u = v.u;
  return (u16)((u + 0x7fffu + ((u >> 16) & 1u)) >> 16);  // RNE
}

__device__ __forceinline__ void gload16(const u16* g, u16* l) {
  __builtin_amdgcn_global_load_lds(
      (const __attribute__((address_space(1))) u32*)g,
      (__attribute__((address_space(3))) u32*)l, 16, 0, 0);
}

// ---------------------------------------------------------------- 4x transpose+convert
// dst[n][k] = bf16(W[k][n]); one 64x64 tile per block; z picks the matrix.
__global__ __launch_bounds__(256) void transpose4_kernel(
    const float* __restrict__ Wq, const float* __restrict__ Wk,
    const float* __restrict__ Wv, const float* __restrict__ Wo,
    u16* __restrict__ wt, u16* __restrict__ wot) {
  __shared__ float tile[64][65];
  const int z = blockIdx.z;
  const float* W = (z == 0) ? Wq : (z == 1) ? Wk : (z == 2) ? Wv : Wo;
  u16* dst = (z < 3) ? (wt + (size_t)z * HID * HID) : wot;
  const int k0 = blockIdx.x * 64, n0 = blockIdx.y * 64;
  for (int i = threadIdx.x; i < 64 * 64; i += 256) {
    const int r = i >> 6, c = i & 63;
    tile[r][c] = W[(size_t)(k0 + r) * HID + n0 + c];
  }
  __syncthreads();
  for (int i = threadIdx.x; i < 64 * 64; i += 256) {
    const int r = i >> 6, c = i & 63;
    dst[(size_t)(n0 + r) * HID + k0 + c] = f2bf(tile[c][r]);
  }
}

// ---------------------------------------------------------------- walk-node weights
__global__ __launch_bounds__(512) void counts_kernel(const int* __restrict__ wn,
                                                     const int* __restrict__ nn,
                                                     float* __restrict__ wgt) {
  __shared__ int cnt[LSEQ];
  __shared__ int sc[2][LSEQ];
  const int b = blockIdx.x, t = threadIdx.x;
  cnt[t] = 0;
  __syncthreads();
  for (int i = t; i < WLEN; i += 512) atomicAdd(&cnt[wn[b * WLEN + i]], 1);
  __syncthreads();
  const int c = cnt[t];
  const int nz = c > 0 ? 1 : 0;
  sc[0][t] = nz;
  __syncthreads();
  int src = 0;
  for (int step = 1; step < LSEQ; step <<= 1) {
    int v = sc[src][t];
    if (t >= step) v += sc[src][t - step];
    sc[src ^ 1][t] = v;
    __syncthreads();
    src ^= 1;
  }
  wgt[b * LSEQ + t] = 0.0f;
  __syncthreads();
  if (nz) {
    const int slot = sc[src][t] - 1;
    wgt[b * LSEQ + slot] = (float)c * (float)nn[b] * (1.0f / WLEN);
  }
}

// ---------------------------------------------------------------- LayerNorm -> bf16
__global__ __launch_bounds__(256) void ln_kernel(const float* __restrict__ x,
                                                 const float* __restrict__ g,
                                                 const float* __restrict__ bb,
                                                 u16* __restrict__ xn) {
  const int w = threadIdx.x >> 6, lane = threadIdx.x & 63;
  const int row = blockIdx.x * 4 + w;
  const float* xr = x + (size_t)row * HID + lane * 12;
  float4 v0 = *(const float4*)(xr);
  float4 v1 = *(const float4*)(xr + 4);
  float4 v2 = *(const float4*)(xr + 8);
  float vv[12] = {v0.x, v0.y, v0.z, v0.w, v1.x, v1.y, v1.z, v1.w, v2.x, v2.y, v2.z, v2.w};
  float s = 0.f, q = 0.f;
#pragma unroll
  for (int j = 0; j < 12; ++j) { s += vv[j]; q += vv[j] * vv[j]; }
#pragma unroll
  for (int d = 1; d < 64; d <<= 1) { s += __shfl_xor(s, d); q += __shfl_xor(q, d); }
  const float mean = s * (1.0f / HID);
  const float var = q * (1.0f / HID) - mean * mean;
  const float rs = rsqrtf(var + 1e-5f);
  const float* gp = g + lane * 12;
  const float* bp = bb + lane * 12;
  u32 pk[6];
#pragma unroll
  for (int j = 0; j < 6; ++j) {
    const u16 lo = f2bf((vv[2 * j] - mean) * rs * gp[2 * j] + bp[2 * j]);
    const u16 hi = f2bf((vv[2 * j + 1] - mean) * rs * gp[2 * j + 1] + bp[2 * j + 1]);
    pk[j] = (u32)lo | ((u32)hi << 16);
  }
  u32* dst = (u32*)(xn + (size_t)row * HID + lane * 12);
#pragma unroll
  for (int j = 0; j < 6; ++j) dst[j] = pk[j];
}

// ---------------------------------------------------------------- MFMA GEMM (m97-style)
// A [M][768] bf16, Bt [N][768] bf16. 128x128 tile, BK=32, global_load_lds staging
// with k-chunk XOR swizzle (both-sides involution: pre-swizzled source + swizzled read).
// MODE 0: QKV epilogue. MODE 1: out = acc + bias -> f32.
template <int MODE>
__global__ __launch_bounds__(256) void gemm_kernel(
    const u16* __restrict__ A, const u16* __restrict__ Bt,
    const float* __restrict__ bias0, const float* __restrict__ bias1,
    const float* __restrict__ bias2, const float* __restrict__ wgt,
    u16* __restrict__ qb, u16* __restrict__ kb, u16* __restrict__ vt,
    float* __restrict__ outf) {
  __shared__ __align__(16) char smem[17408];
  u16* at = (u16*)smem;            // [128][32] u16, swizzled content
  u16* bt = at + 128 * 32;
  const int tid = threadIdx.x;
  const int lane = tid & 63, w = tid >> 6;
  const int wr = w >> 1, wc = w & 1;
  const int fr = lane & 15, fc = lane >> 4;
  const int row0 = blockIdx.x * 128, col0 = blockIdx.y * 128;

  f32x4 acc[4][4];
#pragma unroll
  for (int m = 0; m < 4; ++m)
#pragma unroll
    for (int n = 0; n < 4; ++n) acc[m][n] = (f32x4){0.f, 0.f, 0.f, 0.f};

  // staging: lane l -> LDS row (l>>2), chunk (l&3); source chunk pre-swizzled.
  const int csrc = (((lane & 3) ^ ((lane >> 3) & 3))) * 8;  // u16 offset
  const int lrow = lane >> 2;
  const u16* aS0 = A + (size_t)(row0 + w * 16 + lrow) * HID + csrc;
  const u16* aS1 = A + (size_t)(row0 + 64 + w * 16 + lrow) * HID + csrc;
  const u16* bS0 = Bt + (size_t)(col0 + w * 16 + lrow) * HID + csrc;
  const u16* bS1 = Bt + (size_t)(col0 + 64 + w * 16 + lrow) * HID + csrc;
  u16* atd0 = at + (w * 16) * 32;
  u16* atd1 = at + (64 + w * 16) * 32;
  u16* btd0 = bt + (w * 16) * 32;
  u16* btd1 = bt + (64 + w * 16) * 32;
  const int axor = (fc ^ ((fr >> 1) & 3)) * 8;  // read-side swizzle (u16 offset)

  for (int kt = 0; kt < HID / 32; ++kt) {
    __syncthreads();
    gload16(aS0, atd0); gload16(aS1, atd1);
    gload16(bS0, btd0); gload16(bS1, btd1);
    aS0 += 32; aS1 += 32; bS0 += 32; bS1 += 32;
    __syncthreads();
    short8 af[4], bfr[4];
#pragma unroll
    for (int m = 0; m < 4; ++m)
      af[m] = *(const short8*)(at + (wr * 64 + m * 16 + fr) * 32 + axor);
#pragma unroll
    for (int n = 0; n < 4; ++n)
      bfr[n] = *(const short8*)(bt + (wc * 64 + n * 16 + fr) * 32 + axor);
#pragma unroll
    for (int m = 0; m < 4; ++m)
#pragma unroll
      for (int n = 0; n < 4; ++n) acc[m][n] = MFMA16(af[m], bfr[n], acc[m][n]);
  }

  __syncthreads();  // staging LDS dead; reuse for epilogue repack

  if (MODE == 0) {
    const int reg = blockIdx.y / 6;           // 0=q 1=k 2=v
    const int cloc = (blockIdx.y % 6) * 128;  // col within region
    const int b = row0 >> 9;
    const int tok_base = (row0 & 511) + wr * 64;
    const int hh = ((cloc + wc * 64) >> 6);
    const float* bias = (reg == 0) ? bias0 : (reg == 1) ? bias1 : bias2;
    if (reg == 2) {
      // v: weight-multiplied, transposed [bh][d][tok]; 4 toks contiguous -> 8B stores
#pragma unroll
      for (int m = 0; m < 4; ++m) {
        const int tok0 = tok_base + m * 16 + fc * 4;
        const f32x4 wv = *(const f32x4*)&wgt[b * LSEQ + tok0];
#pragma unroll
        for (int n = 0; n < 4; ++n) {
          const int d = n * 16 + fr;
          const float bval = bias[cloc + wc * 64 + d];
          const u32 p0 = (u32)f2bf((acc[m][n][0] + bval) * wv[0]) |
                         ((u32)f2bf((acc[m][n][1] + bval) * wv[1]) << 16);
          const u32 p1 = (u32)f2bf((acc[m][n][2] + bval) * wv[2]) |
                         ((u32)f2bf((acc[m][n][3] + bval) * wv[3]) << 16);
          u16* dp = vt + (((size_t)(b * NH + hh) * AD + d) * LSEQ + tok0);
          *(uint2*)dp = make_uint2(p0, p1);
        }
      }
    } else {
      // q/k: repack per-wave through LDS -> coalesced 16B row stores [bh][l][d]
      u16* dst = (reg == 0) ? qb : kb;
      const float scl = (reg == 0) ? 0.125f : 1.0f;
      u16* rw = (u16*)smem + w * (16 * 72);
#pragma unroll
      for (int m = 0; m < 4; ++m) {
#pragma unroll
        for (int n = 0; n < 4; ++n) {
          const float bval = bias[cloc + wc * 64 + n * 16 + fr];
#pragma unroll
          for (int r = 0; r < 4; ++r)
            rw[(fc * 4 + r) * 72 + n * 16 + fr] = f2bf((acc[m][n][r] + bval) * scl);
        }
#pragma unroll
        for (int p = 0; p < 2; ++p) {
          const int rr = p * 8 + (lane >> 3);
          const int doff = (lane & 7) * 8;
          const short8 vv = *(const short8*)&rw[rr * 72 + doff];
          const int tok = tok_base + m * 16 + rr;
          *(short8*)(dst + ((size_t)(b * NH + hh) * LSEQ + tok) * AD + doff) = vv;
        }
      }
    }
  } else {
    float* rwf = (float*)smem + w * (16 * 68);
#pragma unroll
    for (int m = 0; m < 4; ++m) {
#pragma unroll
      for (int n = 0; n < 4; ++n) {
        const float bval = bias0[col0 + wc * 64 + n * 16 + fr];
#pragma unroll
        for (int r = 0; r < 4; ++r)
          rwf[(fc * 4 + r) * 68 + n * 16 + fr] = acc[m][n][r] + bval;
      }
#pragma unroll
      for (int p = 0; p < 4; ++p) {
        const int rr = p * 4 + (lane >> 4);
        const int c4 = (lane & 15) * 4;
        const float4 v = *(const float4*)&rwf[rr * 68 + c4];
        const int row = row0 + wr * 64 + m * 16 + rr;
        *(float4*)&outf[(size_t)row * HID + col0 + wc * 64 + c4] = v;
      }
    }
  }
}

// ---------------------------------------------------------------- flash attention
// Swapped QK^T (S^T = K.Q^T) so bias loads are float4 and softmax reduce is
// in-lane + 2 shfl. 4 waves x 16 q-rows; KV tiles of 64; bias reg-double-buffered.
__global__ __launch_bounds__(256) void attn_kernel(const u16* __restrict__ qb,
                                                   const u16* __restrict__ kb,
                                                   const u16* __restrict__ vt,
                                                   const float* __restrict__ bias,
                                                   u16* __restrict__ aout) {
  __shared__ __align__(16) u16 p_lds[4][16][72];
  const int tid = threadIdx.x;
  const int w = tid >> 6, lane = tid & 63;
  const int fr = lane & 15, fc = lane >> 4;
  // XCD-friendly remap: all 8 q-tiles of one (b,h) share blockIdx%8.
  const int x = blockIdx.x;
  const int bh = (x & 7) | ((x >> 6) << 3);
  const int qt = (x >> 3) & 7;
  const int h = bh % NH, b = bh / NH;
  const int q0 = qt * 64 + w * 16;

  const u16* qbase = qb + (size_t)bh * LSEQ * AD;
  const u16* kbase = kb + (size_t)bh * LSEQ * AD;
  const u16* vbase = vt + (size_t)bh * AD * LSEQ;
  const float* brow = bias + (size_t)bh * LSEQ * LSEQ + (size_t)(q0 + fr) * LSEQ + fc * 4;

  const short8 aq0 = *(const short8*)(qbase + (size_t)(q0 + fr) * AD + fc * 8);
  const short8 aq1 = *(const short8*)(qbase + (size_t)(q0 + fr) * AD + 32 + fc * 8);

  f32x4 o[4];
#pragma unroll
  for (int f = 0; f < 4; ++f) o[f] = (f32x4){0.f, 0.f, 0.f, 0.f};
  float m_r = -3.0e38f, l_r = 0.f;

  f32x4 bc[4];
#pragma unroll
  for (int f = 0; f < 4; ++f) bc[f] = *(const f32x4*)(brow + f * 16);

  for (int kt = 0; kt < 8; ++kt) {
    const int kv0 = kt * 64;
    f32x4 s[4];
#pragma unroll
    for (int f = 0; f < 4; ++f) s[f] = bc[f];
    if (kt < 7) {
#pragma unroll
      for (int f = 0; f < 4; ++f) bc[f] = *(const f32x4*)(brow + (kt + 1) * 64 + f * 16);
    }
    // S^T = K . Q^T (+bias already in C): A-frag = K rows, B-frag = Q rows
#pragma unroll
    for (int f = 0; f < 4; ++f) {
      const u16* kp = kbase + (size_t)(kv0 + f * 16 + fr) * AD + fc * 8;
      const short8 k0 = *(const short8*)kp;
      const short8 k1 = *(const short8*)(kp + 32);
      s[f] = MFMA16(k0, aq0, s[f]);
      s[f] = MFMA16(k1, aq1, s[f]);
    }
    // online softmax over k (16 in-lane values + cross-fc lanes)
    float mx = s[0][0];
#pragma unroll
    for (int f = 0; f < 4; ++f)
#pragma unroll
      for (int r = 0; r < 4; ++r) mx = fmaxf(mx, s[f][r]);
    mx = fmaxf(mx, __shfl_xor(mx, 16));
    mx = fmaxf(mx, __shfl_xor(mx, 32));
    const float mn = fmaxf(m_r, mx);
    const float alpha = __expf(m_r - mn);
    m_r = mn;
    float ps = 0.f;
#pragma unroll
    for (int f = 0; f < 4; ++f)
#pragma unroll
      for (int r = 0; r < 4; ++r) {
        const float p = __expf(s[f][r] - mn);
        s[f][r] = p;
        ps += p;
      }
    l_r = l_r * alpha + ps;  // per-lane partial (this fc slice); reduced at end
    // O rows are q=fc*4+r -> fetch their alphas
    float arow[4];
#pragma unroll
    for (int r = 0; r < 4; ++r) arow[r] = __shfl(alpha, fc * 4 + r);
#pragma unroll
    for (int f = 0; f < 4; ++f)
#pragma unroll
      for (int r = 0; r < 4; ++r) o[f][r] *= arow[r];
    // P^T regs -> LDS [q][k] (packed 8B), read back as A-frag of P
#pragma unroll
    for (int f = 0; f < 4; ++f) {
      const u32 p0 = (u32)f2bf(s[f][0]) | ((u32)f2bf(s[f][1]) << 16);
      const u32 p1 = (u32)f2bf(s[f][2]) | ((u32)f2bf(s[f][3]) << 16);
      *(uint2*)&p_lds[w][fr][f * 16 + fc * 4] = make_uint2(p0, p1);
    }
    const short8 pa0 = *(const short8*)&p_lds[w][fr][fc * 8];
    const short8 pa1 = *(const short8*)&p_lds[w][fr][32 + fc * 8];
#pragma unroll
    for (int f = 0; f < 4; ++f) {
      const u16* vp = vbase + (size_t)(f * 16 + fr) * LSEQ + kv0 + fc * 8;
      const short8 v0 = *(const short8*)vp;
      const short8 v1 = *(const short8*)(vp + 32);
      o[f] = MFMA16(pa0, v0, o[f]);
      o[f] = MFMA16(pa1, v1, o[f]);
    }
  }
  float l_tot = l_r;
  l_tot += __shfl_xor(l_tot, 16);
  l_tot += __shfl_xor(l_tot, 32);
  float rinv[4];
#pragma unroll
  for (int r = 0; r < 4; ++r) rinv[r] = 1.0f / __shfl(l_tot, fc * 4 + r);
#pragma unroll
  for (int f = 0; f < 4; ++f)
#pragma unroll
    for (int r = 0; r < 4; ++r) {
      const int row = b * LSEQ + q0 + fc * 4 + r;
      const int col = h * AD + f * 16 + fr;
      aout[(size_t)row * HID + col] = f2bf(o[f][r] * rinv[r]);
    }
}

// ----------------------------------------------------------------
extern "C" void kernel_launch(void* const* d_in, const int* in_sizes, int n_in,
                              void* d_out, int out_size, void* d_ws, size_t ws_size,
                              hipStream_t stream) {
  const float* x = (const float*)d_in[0];
  const float* bias = (const float*)d_in[1];
  const int* wn = (const int*)d_in[2];
  const int* nn = (const int*)d_in[3];
  const float* lng = (const float*)d_in[4];
  const float* lnb = (const float*)d_in[5];
  const float* Wq = (const float*)d_in[6];
  const float* bq = (const float*)d_in[7];
  const float* Wk = (const float*)d_in[8];
  const float* bk = (const float*)d_in[9];
  const float* Wv = (const float*)d_in[10];
  const float* bv = (const float*)d_in[11];
  const float* Wo = (const float*)d_in[12];
  const float* bo = (const float*)d_in[13];
  float* out = (float*)d_out;

  char* ws = (char*)d_ws;
  float* wgt = (float*)ws;                        // 32 KB
  u16* xn = (u16*)(ws + 32768);                   // 8192*768
  u16* wt = xn + (size_t)8192 * 768;              // 2304*768 (Wq^T|Wk^T|Wv^T)
  u16* wot = wt + (size_t)2304 * 768;             // 768*768
  u16* qb = wot + (size_t)768 * 768;              // [bh][l][d]
  u16* kb = qb + (size_t)BS * NH * LSEQ * AD;
  u16* vt = kb + (size_t)BS * NH * LSEQ * AD;     // [bh][d][l]
  u16* aout = xn;  // alias: xn dead after gemm<0>

  hipLaunchKernelGGL(transpose4_kernel, dim3(12, 12, 4), dim3(256), 0, stream,
                     Wq, Wk, Wv, Wo, wt, wot);
  hipLaunchKernelGGL(counts_kernel, dim3(BS), dim3(512), 0, stream, wn, nn, wgt);
  hipLaunchKernelGGL(ln_kernel, dim3(2048), dim3(256), 0, stream, x, lng, lnb, xn);
  hipLaunchKernelGGL((gemm_kernel<0>), dim3(64, 18), dim3(256), 0, stream, xn, wt,
                     bq, bk, bv, wgt, qb, kb, vt, (float*)nullptr);
  hipLaunchKernelGGL(attn_kernel, dim3(1536), dim3(256), 0, stream, qb, kb, vt, bias, aout);
  hipLaunchKernelGGL((gemm_kernel<1>), dim3(64, 6), dim3(256), 0, stream, aout, wot,
                     bo, (const float*)nullptr, (const float*)nullptr,
                     (const float*)nullptr, (u16*)nullptr, (u16*)nullptr,
                     (u16*)nullptr, out);
}